// Round 2
// baseline (272.810 us; speedup 1.0000x reference)
//
#include <hip/hip_runtime.h>
#include <hip/hip_bf16.h>

constexpr int BN = 8, HH = 512, WW = 512;
constexpr int PIX = HH * WW;
constexpr float EPSF = 1e-4f;

__device__ __forceinline__ float b2f(__hip_bfloat16 x) { return __bfloat162float(x); }
__device__ __forceinline__ __hip_bfloat16 f2b(float x) { return __float2bfloat16(x); }
__device__ __forceinline__ unsigned short bfbits(float x) {
    union { __hip_bfloat16 b; unsigned short u; } cv; cv.b = f2b(x); return cv.u;
}

typedef __attribute__((ext_vector_type(8))) short bf16x8;   // MFMA A/B frag (4 VGPRs)
typedef __attribute__((ext_vector_type(4))) float f32x4;    // MFMA C/D frag

// ---- workspace float offsets (small region) ----
constexpr int OFF_TOT = 0;       // 8*16 per-image channel totals (atomics)
constexpr int OFF_ROW0 = 128;
constexpr int OFF_ROW1 = 256;
constexpr int OFF_COL0 = 384;
constexpr int OFF_COL1 = 512;
constexpr int OFF_COR = 640;     // corners [b][hi][wi][16]
constexpr int OFF_WR  = 2048;    // A-fragment weights hi(2560 bf16) + lo(2560 bf16)
constexpr int OFF_EH  = 4608;    // 8*37
constexpr int OFF_CH  = 5120;    // 8*37
// ---- big buffers: only tpl (xg computed on the fly in horiz) ----
constexpr size_t OFF_TPB = 65536;                          // tpl fp32 (4 planes)
constexpr size_t TP_BYTES = (size_t)4 * BN * PIX * 4;      // 33,554,432
constexpr size_t WS_NEEDED = OFF_TPB + TP_BYTES;           // ~33.6 MB (134 MB proven)

// ---------------- prep: zero atomic slots, swizzle w2 into hi/lo A-fragments ----------------
// hi = rn-bf16(w), lo = rn-bf16(w - hi): split keeps mean(s) at ~fp32 accuracy (round-4 lesson:
// bf16-only w2 flips the discontinuous ceil() in fs -> pi-flips in Hf).
__global__ void prep_kernel(const float* __restrict__ w2, float* __restrict__ wsf) {
    int t = threadIdx.x;
    for (int i = t; i < 640; i += 256) wsf[i] = 0.f;
    unsigned short* ab = (unsigned short*)(wsf + OFF_WR);
    for (int idx = t; idx < 5120; idx += 256) {
        int part = idx / 2560;               // 0 = hi, 1 = lo
        int id = idx - part * 2560;
        int ks = id >> 9, rem = id & 511, lane = rem >> 3, j = id & 7;
        int oc = lane & 15, q = lane >> 4;
        int k = q * 8 + j;
        int tap = 2 * ks + (k >> 4), ic = k & 15;
        float val = (tap <= 8) ? w2[oc * 144 + ic * 9 + tap] : 0.f;
        float hv = b2f(f2b(val));
        ab[idx] = (part == 0) ? bfbits(val) : bfbits(val - hv);
    }
}

// conv1 for one pixel given its 27-value receptive field -> packed bf16 pair words
__device__ __forceinline__ void conv1_px(const float v[27], const float* __restrict__ w1,
                                         const float* __restrict__ b1, unsigned int u[8]) {
    float o[16];
#pragma unroll
    for (int oc = 0; oc < 16; oc++) {
        float a = b1[oc];
#pragma unroll
        for (int j = 0; j < 27; j++) a += v[j] * w1[oc * 27 + j];
        o[oc] = a / (1.f + __expf(-a));
    }
#pragma unroll
    for (int k = 0; k < 8; k++)
        u[k] = (unsigned int)bfbits(o[2 * k]) | ((unsigned int)bfbits(o[2 * k + 1]) << 16);
}

// ---------------- fused conv1+conv2(+RGB) with conv3-mean reduction ----------------
// Round-5 restructure: 8-row tiles (grid y=64), batch halo staged in LDS (coalesced,
// zero-padded), conv1+RGB read LDS. LDS 38.4->31.2 KB => ~5 blocks/CU (was ~2).
// CRITICAL (round-1 bug): h1 pixels OUTSIDE the image must be exactly 0 (conv2's
// zero padding) -- NOT silu(b1) from a zero-padded batch window.
__global__ __launch_bounds__(256) void conv12_kernel(const float* __restrict__ batch,
                                                     const float* __restrict__ w1,
                                                     const float* __restrict__ b1,
                                                     const unsigned short* __restrict__ abuf,
                                                     const float* __restrict__ b2v,
                                                     const float* __restrict__ gcm,
                                                     float* __restrict__ wsf,
                                                     float* __restrict__ out) {
    __shared__ float st[3][12][68];        // batch halo: rows h0-2..h0+9, cols w0-2..w0+65
    __shared__ uint4 h1s[10 * 66 * 2];
    __shared__ float part[4][16];

    int tx = threadIdx.x;
    int lane = tx & 63, wave = tx >> 6;
    int n = lane & 15, q = lane >> 4;
    int w0 = blockIdx.x * 64, h0 = blockIdx.y * 8, b = blockIdx.z;

    union { uint4 u; bf16x8 v; } cv;
    bf16x8 ah[5], al[5];
    const uint4* ab4 = (const uint4*)abuf;
#pragma unroll
    for (int ks = 0; ks < 5; ks++) {
        cv.u = ab4[ks * 64 + lane];       ah[ks] = cv.v;
        cv.u = ab4[320 + ks * 64 + lane]; al[ks] = cv.v;
    }

    const float* pb = batch + (size_t)(b * 3) * PIX;

    // ---- stage batch halo tile into LDS (coalesced, zero-padded) ----
    for (int i = tx; i < 2448; i += 256) {           // 3 ch * 12 rows * 68 cols
        int ch = i / 816;
        int rem = i - ch * 816;
        int r = rem / 68, c = rem - r * 68;
        int gh = h0 - 2 + r, gw = w0 - 2 + c;
        float v = 0.f;
        if (gh >= 0 && gh < HH && gw >= 0 && gw < WW)
            v = pb[(size_t)ch * PIX + (size_t)gh * WW + gw];
        st[ch][r][c] = v;
    }
    __syncthreads();

    // ---- conv1 over the 10x66 h1 halo, inputs from LDS ----
    for (int i = tx; i < 660; i += 256) {
        int r = i / 66, c = i - r * 66;              // h1 pixel (h0-1+r, w0-1+c)
        int gh = h0 - 1 + r, gw = w0 - 1 + c;
        unsigned int u[8];
        if (gh >= 0 && gh < HH && gw >= 0 && gw < WW) {
            float v[27];
#pragma unroll
            for (int ic = 0; ic < 3; ic++)
#pragma unroll
                for (int kh = 0; kh < 3; kh++)
#pragma unroll
                    for (int kw = 0; kw < 3; kw++)
                        v[ic * 9 + kh * 3 + kw] = st[ic][r + kh][c + kw];
            conv1_px(v, w1, b1, u);
        } else {
#pragma unroll
            for (int k = 0; k < 8; k++) u[k] = 0u;   // conv2 zero padding
        }
        int swz = (c >> 2) & 1;
        int base = i * 2;
        h1s[base + swz]       = make_uint4(u[0], u[1], u[2], u[3]);
        h1s[base + (swz ^ 1)] = make_uint4(u[4], u[5], u[6], u[7]);
    }

    // ---- RGB order channels, inputs from staged LDS ----
    for (int j = tx; j < 512; j += 256) {
        int rr = j >> 6, ccx = j & 63;
        float v0 = st[0][rr + 2][ccx + 2];
        float v1 = st[1][rr + 2][ccx + 2];
        float v2 = st[2][rr + 2][ccx + 2];
        int mx  = (v0 >= v1 && v0 >= v2) ? 0 : ((v1 >= v2) ? 1 : 2);
        int mx2 = (v2 >= v1 && v2 >= v0) ? 2 : ((v1 >= v0) ? 1 : 0);
        int mn  = (v0 <= v1 && v0 <= v2) ? 0 : ((v1 <= v2) ? 1 : 2);
        int mn2 = (v2 <= v1 && v2 <= v0) ? 2 : ((v1 <= v0) ? 1 : 0);
        size_t p = (size_t)(h0 + rr) * WW + (w0 + ccx);
#pragma unroll
        for (int c = 0; c < 3; c++) {
            float r = 0.5f * ((float)(c == mx) + (float)(c == mx2))
                    - 0.5f * ((float)(c == mn) + (float)(c == mn2));
            out[(size_t)(b * 6 + 2 + c) * PIX + p] = r;
        }
    }
    __syncthreads();

    float tt[4] = {0, 0, 0, 0};
    float cs0[4] = {0, 0, 0, 0};
    float cs1[4] = {0, 0, 0, 0};
    for (int rloc = 0; rloc < 2; rloc++) {
        int row = wave * 2 + rloc;
        int grow = h0 + row;
        f32x4 acc[4] = {{0,0,0,0},{0,0,0,0},{0,0,0,0},{0,0,0,0}};
#pragma unroll
        for (int ks = 0; ks < 5; ks++) {
            int tap = 2 * ks + (q >> 1); if (tap > 8) tap = 8;
            int dh = tap / 3 - 1, dw = tap % 3 - 1;
            int half = q & 1;
            int lr = row + 1 + dh;
#pragma unroll
            for (int t = 0; t < 4; t++) {
                int c = 1 + dw + t * 16 + n;
                cv.u = h1s[(lr * 66 + c) * 2 + (half ^ ((c >> 2) & 1))];
                acc[t] = __builtin_amdgcn_mfma_f32_16x16x32_bf16(ah[ks], cv.v, acc[t], 0, 0, 0);
                acc[t] = __builtin_amdgcn_mfma_f32_16x16x32_bf16(al[ks], cv.v, acc[t], 0, 0, 0);
            }
        }
        float sv[4][4];
#pragma unroll
        for (int t = 0; t < 4; t++)
#pragma unroll
            for (int r = 0; r < 4; r++) {
                float a = acc[t][r] + b2v[q * 4 + r];
                sv[t][r] = a / (1.f + __expf(-a));
            }
#pragma unroll
        for (int r = 0; r < 4; r++) tt[r] += sv[0][r] + sv[1][r] + sv[2][r] + sv[3][r];
        if (grow == 0 || grow == HH - 1) {
            int off = (grow == 0) ? OFF_ROW0 : OFF_ROW1;
#pragma unroll
            for (int r = 0; r < 4; r++) {
                float x = sv[0][r] + sv[1][r] + sv[2][r] + sv[3][r];
#pragma unroll
                for (int d = 1; d < 16; d <<= 1) x += __shfl_xor(x, d, 64);
                if (n == 0) atomicAdd(&wsf[off + b * 16 + q * 4 + r], x);
            }
        }
        if (blockIdx.x == 0 && n == 0)
#pragma unroll
            for (int r = 0; r < 4; r++) cs0[r] += sv[0][r];
        if (blockIdx.x == 7 && n == 15)
#pragma unroll
            for (int r = 0; r < 4; r++) cs1[r] += sv[3][r];
        if ((grow == 0 || grow == HH - 1)) {
            int hi = (grow == 0) ? 0 : 1;
            if (blockIdx.x == 0 && n == 0)
#pragma unroll
                for (int r = 0; r < 4; r++)
                    wsf[OFF_COR + ((b * 2 + hi) * 2 + 0) * 16 + q * 4 + r] = sv[0][r];
            if (blockIdx.x == 7 && n == 15)
#pragma unroll
                for (int r = 0; r < 4; r++)
                    wsf[OFF_COR + ((b * 2 + hi) * 2 + 1) * 16 + q * 4 + r] = sv[3][r];
        }
    }
    if (blockIdx.x == 0 && n == 0)
#pragma unroll
        for (int r = 0; r < 4; r++) atomicAdd(&wsf[OFF_COL0 + b * 16 + q * 4 + r], cs0[r]);
    if (blockIdx.x == 7 && n == 15)
#pragma unroll
        for (int r = 0; r < 4; r++) atomicAdd(&wsf[OFF_COL1 + b * 16 + q * 4 + r], cs1[r]);
#pragma unroll
    for (int r = 0; r < 4; r++) {
        float x = tt[r];
#pragma unroll
        for (int d = 1; d < 16; d <<= 1) x += __shfl_xor(x, d, 64);
        tt[r] = x;
    }
    if (n == 0)
#pragma unroll
        for (int r = 0; r < 4; r++) part[wave][q * 4 + r] = tt[r];
    __syncthreads();
    if (tx < 16)
        atomicAdd(&wsf[OFF_TOT + b * 16 + tx],
                  part[0][tx] + part[1][tx] + part[2][tx] + part[3][tx]);
}

// ---------------- filter: assemble mean via edge algebra, build separable taps ----------------
__global__ void filter_kernel(const float* __restrict__ w3, const float* __restrict__ b3,
                              float* __restrict__ wsf) {
    int b = blockIdx.x, t = threadIdx.x;   // 160 threads
    __shared__ float red[160];
    float val = 0.f;
    if (t < 144) {
        int ic = t / 9, tap = t % 9, kh = tap / 3, kw = tap % 3;
        float T = wsf[OFF_TOT + b * 16 + ic];
        int hi = -1, wi = -1;
        if (kh == 0) { T -= wsf[OFF_ROW1 + b * 16 + ic]; hi = 1; }
        else if (kh == 2) { T -= wsf[OFF_ROW0 + b * 16 + ic]; hi = 0; }
        if (kw == 0) { T -= wsf[OFF_COL1 + b * 16 + ic]; wi = 1; }
        else if (kw == 2) { T -= wsf[OFF_COL0 + b * 16 + ic]; wi = 0; }
        if (hi >= 0 && wi >= 0) T += wsf[OFF_COR + ((b * 2 + hi) * 2 + wi) * 16 + ic];
        val = w3[t] * T;
    }
    red[t] = val;
    __syncthreads();
    __shared__ float sh_mean;
    if (t == 0) {
        float S = 0.f;
        for (int i = 0; i < 144; i++) S += red[i];
        sh_mean = b3[0] + S * (1.f / (float)PIX);
    }
    __syncthreads();
    float scale = fminf(2.5f, fmaxf(-2.5f, sh_mean));
    float sd = exp2f(scale);
    float fs = ceilf(3.f * sd + 0.5f);
    float e = 0.f, c = 0.f;
    if (t < 37) {
        float x = (float)(t - 18);
        if (fabsf(x) <= fs) {
            float qq = x / sd;
            e = __expf(-0.5f * qq * qq);
            c = -x / (sd * sd * sd * 6.28318530717958647692f) * e;
        }
    }
    __shared__ float sa[40], sb[40];
    if (t < 37) { sa[t] = e; sb[t] = fabsf(c); }
    __syncthreads();
    __shared__ float Se, Sc;
    if (t == 0) {
        float a = 0.f, d = 0.f;
        for (int i = 0; i < 37; i++) { a += sa[i]; d += sb[i]; }
        Se = a; Sc = d;
    }
    __syncthreads();
    if (t < 37) {
        wsf[OFF_EH + b * 37 + t] = e / Se;
        wsf[OFF_CH + b * 37 + t] = c / Sc;
    }
}

// ---------------- horizontal pass: batch -> xg (on the fly) -> t0..t3 ----------------
// Block = 2 rows x 512 cols, 4 px/thread sliding window. Skewed LDS (+1 word per 32)
// breaks the stride-4 8-way bank conflict. Small live set: 16 accumulators, no spill.
__device__ __forceinline__ int skw(int c) { return c + (c >> 5); }
__global__ __launch_bounds__(256, 4) void horiz_kernel(const float* __restrict__ batch,
                                                       const float* __restrict__ gcm,
                                                       const float* __restrict__ ehat,
                                                       const float* __restrict__ chat,
                                                       float* __restrict__ t) {
    __shared__ float xr[2][3][566];        // skewed: logical col 0..547 -> skw(c)
    int tx = threadIdx.x;
    int h0 = blockIdx.x * 2;
    int b  = blockIdx.y;
    const float* pb = batch + (size_t)(b * 3) * PIX;
    float g0 = gcm[0], g1 = gcm[1], g2 = gcm[2];
    float g3 = gcm[3], g4 = gcm[4], g5 = gcm[5];
    float g6 = gcm[6], g7 = gcm[7], g8 = gcm[8];
    for (int i = tx; i < 2 * 548; i += 256) {
        int r = i / 548, c = i - r * 548;
        int gw = c - 18;
        float v0 = 0.f, v1 = 0.f, v2 = 0.f;
        if (gw >= 0 && gw < WW) {
            size_t p = (size_t)(h0 + r) * WW + gw;
            v0 = pb[p]; v1 = pb[(size_t)PIX + p]; v2 = pb[2 * (size_t)PIX + p];
        }
        int cs = skw(c);
        xr[r][0][cs] = g0 * v0 + g1 * v1 + g2 * v2;
        xr[r][1][cs] = g3 * v0 + g4 * v1 + g5 * v2;
        xr[r][2][cs] = g6 * v0 + g7 * v1 + g8 * v2;
    }
    __syncthreads();
    int r = tx >> 7, colbase = (tx & 127) * 4;
    const float* eh = ehat + b * 37; const float* ch = chat + b * 37;
    float a0[4] = {}, a1[4] = {}, a2[4] = {}, a3[4] = {};
#pragma unroll 4
    for (int kk = 0; kk < 40; kk++) {
        int cs = skw(colbase + kk);
        float x0 = xr[r][0][cs], x1 = xr[r][1][cs], x2 = xr[r][2][cs];
#pragma unroll
        for (int i = 0; i < 4; i++) {
            int k = kk - i;
            if (k >= 0 && k < 37) {          // compile-time after unroll
                float ce = eh[k], cc = ch[k];
                a0[i] += ce * x0; a1[i] += ce * x1;
                a2[i] += ce * x2; a3[i] += cc * x0;
            }
        }
    }
    const size_t PL = (size_t)BN * PIX;
    size_t p = (size_t)b * PIX + (size_t)(h0 + r) * WW + colbase;
    *(float4*)&t[0 * PL + p] = make_float4(a0[0], a0[1], a0[2], a0[3]);
    *(float4*)&t[1 * PL + p] = make_float4(a1[0], a1[1], a1[2], a1[3]);
    *(float4*)&t[2 * PL + p] = make_float4(a2[0], a2[1], a2[2], a2[3]);
    *(float4*)&t[3 * PL + p] = make_float4(a3[0], a3[1], a3[2], a3[3]);
}

// ---------------- vertical pass + final math -> out ch0,1,5 (4-row sliding/thread) ----------------
__global__ __launch_bounds__(256, 4) void vert_kernel(const float* __restrict__ t,
                                                      const float* __restrict__ ehat,
                                                      const float* __restrict__ chat,
                                                      float* __restrict__ out) {
    int tx = threadIdx.x;
    int j = blockIdx.x * 64 + (tx & 63);
    int r0 = (blockIdx.y * 4 + (tx >> 6)) * 4;
    int b = blockIdx.z;
    const float* eh = ehat + b * 37; const float* ch = chat + b * 37;
    const size_t PL = (size_t)BN * PIX;
    const float* t0 = t + (size_t)b * PIX;
    float E[4] = {}, Ex[4] = {}, Ey[4] = {}, El[4] = {}, Ell[4] = {};
#pragma unroll 4
    for (int kk = 0; kk < 40; kk++) {
        int gr = r0 - 18 + kk;
        if (gr >= 0 && gr < HH) {
            size_t idx = (size_t)gr * WW + j;
            float v0 = t0[idx], v1 = t0[PL + idx], v2 = t0[2 * PL + idx], v3 = t0[3 * PL + idx];
#pragma unroll
            for (int i = 0; i < 4; i++) {
                int k = kk - i;
                if (k >= 0 && k < 37) {
                    float ce = eh[k], cc = ch[k];
                    E[i] += ce * v0; Ex[i] += cc * v0; Ey[i] += ce * v3;
                    El[i] += ce * v1; Ell[i] += ce * v2;
                }
            }
        }
    }
#pragma unroll
    for (int i = 0; i < 4; i++) {
        int h = r0 + i;
        float Hf = atanf(El[i] / (Ell[i] + EPSF));
        float S = logf((El[i] * El[i] + Ell[i] * Ell[i]) / (E[i] * E[i] + EPSF) + EPSF);
        float rx = Ex[i] / (E[i] + EPSF), ry = Ey[i] / (E[i] + EPSF);
        float Wv = atanf(rx * rx + ry * ry);
        size_t base = (size_t)(b * 6) * PIX + (size_t)h * WW + j;
        out[base] = Hf;
        out[base + PIX] = S;
        out[base + 5 * (size_t)PIX] = Wv;
    }
}

extern "C" void kernel_launch(void* const* d_in, const int* in_sizes, int n_in,
                              void* d_out, int out_size, void* d_ws, size_t ws_size,
                              hipStream_t stream) {
    const float* batch = (const float*)d_in[0];
    const float* gcm   = (const float*)d_in[1];
    const float* w1    = (const float*)d_in[2];
    const float* b1    = (const float*)d_in[3];
    const float* w2    = (const float*)d_in[4];
    const float* b2    = (const float*)d_in[5];
    const float* w3    = (const float*)d_in[6];
    const float* b3    = (const float*)d_in[7];
    float* out = (float*)d_out;

    if (ws_size < WS_NEEDED) return;

    float* wsf = (float*)d_ws;
    float* tpl = (float*)((char*)d_ws + OFF_TPB);
    float* ehat = wsf + OFF_EH;
    float* chat = wsf + OFF_CH;

    prep_kernel<<<dim3(1), dim3(256), 0, stream>>>(w2, wsf);
    conv12_kernel<<<dim3(8, 64, 8), dim3(256), 0, stream>>>(
        batch, w1, b1, (const unsigned short*)(wsf + OFF_WR), b2, gcm, wsf, out);
    filter_kernel<<<dim3(8), dim3(160), 0, stream>>>(w3, b3, wsf);
    horiz_kernel<<<dim3(256, 8), dim3(256), 0, stream>>>(batch, gcm, ehat, chat, tpl);
    vert_kernel<<<dim3(8, 32, 8), dim3(256), 0, stream>>>(tpl, ehat, chat, out);
}

// Round 3
// 251.495 us; speedup vs baseline: 1.0848x; 1.0848x over previous
//
#include <hip/hip_runtime.h>
#include <hip/hip_bf16.h>

constexpr int BN = 8, HH = 512, WW = 512;
constexpr int PIX = HH * WW;
constexpr float EPSF = 1e-4f;

__device__ __forceinline__ float b2f(__hip_bfloat16 x) { return __bfloat162float(x); }
__device__ __forceinline__ __hip_bfloat16 f2b(float x) { return __float2bfloat16(x); }
__device__ __forceinline__ unsigned short bfbits(float x) {
    union { __hip_bfloat16 b; unsigned short u; } cv; cv.b = f2b(x); return cv.u;
}
// hardware packed f32->bf16 (RNE), 1 instr instead of ~16
__device__ __forceinline__ unsigned int cvtpk(float lo, float hi) {
    unsigned int r;
    asm("v_cvt_pk_bf16_f32 %0, %1, %2" : "=v"(r) : "v"(lo), "v"(hi));
    return r;
}
// silu via hw rcp (h is bf16-quantized downstream; ~2^-22 rel err invisible)
__device__ __forceinline__ float silu(float a) {
    return a * __builtin_amdgcn_rcpf(1.f + __expf(-a));
}

typedef __attribute__((ext_vector_type(8))) short bf16x8;   // MFMA A/B frag (4 VGPRs)
typedef __attribute__((ext_vector_type(4))) float f32x4;    // MFMA C/D frag

// ---- workspace float offsets (small region) ----
constexpr int OFF_TOT = 0;       // 8*16 per-image channel totals (atomics)
constexpr int OFF_ROW0 = 128;
constexpr int OFF_ROW1 = 256;
constexpr int OFF_COL0 = 384;
constexpr int OFF_COL1 = 512;
constexpr int OFF_COR = 640;     // corners [b][hi][wi][16] -> 640..1151
constexpr int OFF_W1R = 1280;    // w1 A-frags hi(512 bf16)+lo(512 bf16) = 512 floats
constexpr int OFF_WR  = 2048;    // w2 A-frags hi(2560 bf16) + lo(2560 bf16)
constexpr int OFF_EH  = 4608;    // 8*37
constexpr int OFF_CH  = 5120;    // 8*37
// ---- big buffers: only tpl (xg computed on the fly in horiz) ----
constexpr size_t OFF_TPB = 65536;                          // tpl fp32 (4 planes)
constexpr size_t TP_BYTES = (size_t)4 * BN * PIX * 4;      // 33,554,432
constexpr size_t WS_NEEDED = OFF_TPB + TP_BYTES;           // ~33.6 MB (134 MB proven)

// ---------------- prep: zero atomic slots, swizzle w1/w2 into hi/lo A-fragments ----------------
// hi = rn-bf16(w), lo = rn-bf16(w - hi): split keeps the ceil(3sd+0.5) path at ~fp32 accuracy
// (bf16-only weights flip the discontinuity -> pi-flips in Hf).
__global__ void prep_kernel(const float* __restrict__ w1, const float* __restrict__ w2,
                            float* __restrict__ wsf) {
    int t = threadIdx.x;
    for (int i = t; i < 640; i += 256) wsf[i] = 0.f;
    // w2 A-frags (conv2): A[oc][k], k = (tap_local)*16 + ic within each K=32 chunk ks
    unsigned short* ab = (unsigned short*)(wsf + OFF_WR);
    for (int idx = t; idx < 5120; idx += 256) {
        int part = idx / 2560;               // 0 = hi, 1 = lo
        int id = idx - part * 2560;
        int ks = id >> 9, rem = id & 511, lane = rem >> 3, j = id & 7;
        int oc = lane & 15, q = lane >> 4;
        int k = q * 8 + j;
        int tap = 2 * ks + (k >> 4), ic = k & 15;
        float val = (tap <= 8) ? w2[oc * 144 + ic * 9 + tap] : 0.f;
        float hv = b2f(f2b(val));
        ab[idx] = (part == 0) ? bfbits(val) : bfbits(val - hv);
    }
    // w1 A-frags (conv1): A[oc][k], k = ic*9 + kh*3 + kw (0..26), pad to 32 with zeros
    unsigned short* a1 = (unsigned short*)(wsf + OFF_W1R);
    for (int idx = t; idx < 1024; idx += 256) {
        int part = idx >> 9;                 // 0 = hi, 1 = lo
        int id = idx & 511;
        int lane = id >> 3, j = id & 7;
        int oc = lane & 15, q = lane >> 4;
        int k = q * 8 + j;
        float val = (k < 27) ? w1[oc * 27 + k] : 0.f;
        float hv = b2f(f2b(val));
        a1[idx] = (part == 0) ? bfbits(val) : bfbits(val - hv);
    }
}

// ---------------- fused conv1(MFMA)+conv2(MFMA)+RGB with conv3-mean reduction ----------------
// Round-3: conv1 via mfma_f32_16x16x32_bf16 (w1 hi/lo x bf16 inputs), replacing the
// ~1000-VALU-instr/px scalar path. B-frag: lane(q,n) supplies input k=q*8+j of halo
// pixel i=g*16+n, read from the fp32 LDS batch tile and packed with v_cvt_pk_bf16_f32.
// CRITICAL: h1 pixels OUTSIDE the image must be exactly 0 (conv2's zero padding);
// padded-K B values masked to 0 (A=0 there, but NaN*0=NaN in MFMA).
__global__ __launch_bounds__(256) void conv12_kernel(const float* __restrict__ batch,
                                                     const unsigned short* __restrict__ w1buf,
                                                     const float* __restrict__ b1,
                                                     const unsigned short* __restrict__ abuf,
                                                     const float* __restrict__ b2v,
                                                     float* __restrict__ wsf,
                                                     float* __restrict__ out) {
    __shared__ float st[3][12][68];        // batch halo: rows h0-2..h0+9, cols w0-2..w0+65
    __shared__ uint4 h1s[10 * 66 * 2];
    __shared__ float part[4][16];

    int tx = threadIdx.x;
    int lane = tx & 63, wave = tx >> 6;
    int n = lane & 15, q = lane >> 4;
    int w0 = blockIdx.x * 64, h0 = blockIdx.y * 8, b = blockIdx.z;

    union { uint4 u; bf16x8 v; } cv;
    const float* pb = batch + (size_t)(b * 3) * PIX;

    // ---- stage batch halo tile into LDS (coalesced, zero-padded) ----
    for (int i = tx; i < 2448; i += 256) {           // 3 ch * 12 rows * 68 cols
        int ch = i / 816;
        int rem = i - ch * 816;
        int r = rem / 68, c = rem - r * 68;
        int gh = h0 - 2 + r, gw = w0 - 2 + c;
        float v = 0.f;
        if (gh >= 0 && gh < HH && gw >= 0 && gw < WW)
            v = pb[(size_t)ch * PIX + (size_t)gh * WW + gw];
        st[ch][r][c] = v;
    }

    // per-lane conv1 constants (independent of groups)
    bf16x8 w1h, w1l;
    const uint4* w14 = (const uint4*)w1buf;
    cv.u = w14[lane];      w1h = cv.v;
    cv.u = w14[64 + lane]; w1l = cv.v;
    int koff[8];
#pragma unroll
    for (int j = 0; j < 8; j++) {
        int k = q * 8 + j;
        int kk = (k < 27) ? k : 0;
        int ic = kk / 9, rem = kk - ic * 9, kh = rem / 3, kw = rem - kh * 3;
        koff[j] = ic * 816 + kh * 68 + kw;
    }
    float b1q[4];
#pragma unroll
    for (int r = 0; r < 4; r++) b1q[r] = b1[q * 4 + r];
    bool hiq = (q == 3);
    __syncthreads();

    // ---- conv1 via MFMA over the 10x66 h1 halo (660 px, 42 groups of 16) ----
    const float* stf = &st[0][0][0];
    unsigned int* hw = (unsigned int*)h1s;
    for (int g = wave; g < 42; g += 4) {
        int i = g * 16 + n; if (i > 659) i = 659;    // clamp: dup writes same data
        int r = i / 66, c = i - r * 66;              // h1 pixel (h0-1+r, w0-1+c)
        int base = r * 68 + c;
        float x[8];
#pragma unroll
        for (int j = 0; j < 8; j++) x[j] = stf[base + koff[j]];
#pragma unroll
        for (int j = 3; j < 8; j++) x[j] = hiq ? 0.f : x[j];   // k>=27 -> finite 0
        union { unsigned int w[4]; bf16x8 v; } bb;
        bb.w[0] = cvtpk(x[0], x[1]);
        bb.w[1] = cvtpk(x[2], x[3]);
        bb.w[2] = cvtpk(x[4], x[5]);
        bb.w[3] = cvtpk(x[6], x[7]);
        f32x4 a = {0, 0, 0, 0};
        a = __builtin_amdgcn_mfma_f32_16x16x32_bf16(w1h, bb.v, a, 0, 0, 0);
        a = __builtin_amdgcn_mfma_f32_16x16x32_bf16(w1l, bb.v, a, 0, 0, 0);
        int gh = h0 - 1 + r, gw = w0 - 1 + c;
        bool ok = ((unsigned)gh < (unsigned)HH) && ((unsigned)gw < (unsigned)WW);
        unsigned int p0 = cvtpk(silu(a[0] + b1q[0]), silu(a[1] + b1q[1]));
        unsigned int p1 = cvtpk(silu(a[2] + b1q[2]), silu(a[3] + b1q[3]));
        p0 = ok ? p0 : 0u;                           // conv2 zero padding
        p1 = ok ? p1 : 0u;
        int swz = (c >> 2) & 1;
        int slot = i * 2 + ((q >= 2) ? (swz ^ 1) : swz);
        *(uint2*)&hw[slot * 4 + (q & 1) * 2] = make_uint2(p0, p1);
    }

    // ---- RGB order channels, inputs from staged fp32 LDS (exact compares) ----
    for (int j = tx; j < 512; j += 256) {
        int rr = j >> 6, ccx = j & 63;
        float v0 = st[0][rr + 2][ccx + 2];
        float v1 = st[1][rr + 2][ccx + 2];
        float v2 = st[2][rr + 2][ccx + 2];
        int mx  = (v0 >= v1 && v0 >= v2) ? 0 : ((v1 >= v2) ? 1 : 2);
        int mx2 = (v2 >= v1 && v2 >= v0) ? 2 : ((v1 >= v0) ? 1 : 0);
        int mn  = (v0 <= v1 && v0 <= v2) ? 0 : ((v1 <= v2) ? 1 : 2);
        int mn2 = (v2 <= v1 && v2 <= v0) ? 2 : ((v1 <= v0) ? 1 : 0);
        size_t p = (size_t)(h0 + rr) * WW + (w0 + ccx);
#pragma unroll
        for (int c = 0; c < 3; c++) {
            float r = 0.5f * ((float)(c == mx) + (float)(c == mx2))
                    - 0.5f * ((float)(c == mn) + (float)(c == mn2));
            out[(size_t)(b * 6 + 2 + c) * PIX + p] = r;
        }
    }
    __syncthreads();

    // ---- conv2 via MFMA + silu + conv3-mean reductions ----
    bf16x8 ah[5], al[5];
    const uint4* ab4 = (const uint4*)abuf;
#pragma unroll
    for (int ks = 0; ks < 5; ks++) {
        cv.u = ab4[ks * 64 + lane];       ah[ks] = cv.v;
        cv.u = ab4[320 + ks * 64 + lane]; al[ks] = cv.v;
    }
    float b2q[4];
#pragma unroll
    for (int r = 0; r < 4; r++) b2q[r] = b2v[q * 4 + r];

    float tt[4] = {0, 0, 0, 0};
    float cs0[4] = {0, 0, 0, 0};
    float cs1[4] = {0, 0, 0, 0};
    for (int rloc = 0; rloc < 2; rloc++) {
        int row = wave * 2 + rloc;
        int grow = h0 + row;
        f32x4 acc[4] = {{0,0,0,0},{0,0,0,0},{0,0,0,0},{0,0,0,0}};
#pragma unroll
        for (int ks = 0; ks < 5; ks++) {
            int tap = 2 * ks + (q >> 1); if (tap > 8) tap = 8;
            int dh = tap / 3 - 1, dw = tap % 3 - 1;
            int half = q & 1;
            int lr = row + 1 + dh;
#pragma unroll
            for (int t = 0; t < 4; t++) {
                int c = 1 + dw + t * 16 + n;
                cv.u = h1s[(lr * 66 + c) * 2 + (half ^ ((c >> 2) & 1))];
                acc[t] = __builtin_amdgcn_mfma_f32_16x16x32_bf16(ah[ks], cv.v, acc[t], 0, 0, 0);
                acc[t] = __builtin_amdgcn_mfma_f32_16x16x32_bf16(al[ks], cv.v, acc[t], 0, 0, 0);
            }
        }
        float sv[4][4];
#pragma unroll
        for (int t = 0; t < 4; t++)
#pragma unroll
            for (int r = 0; r < 4; r++)
                sv[t][r] = silu(acc[t][r] + b2q[r]);
#pragma unroll
        for (int r = 0; r < 4; r++) tt[r] += sv[0][r] + sv[1][r] + sv[2][r] + sv[3][r];
        if (grow == 0 || grow == HH - 1) {
            int off = (grow == 0) ? OFF_ROW0 : OFF_ROW1;
#pragma unroll
            for (int r = 0; r < 4; r++) {
                float x = sv[0][r] + sv[1][r] + sv[2][r] + sv[3][r];
#pragma unroll
                for (int d = 1; d < 16; d <<= 1) x += __shfl_xor(x, d, 64);
                if (n == 0) atomicAdd(&wsf[off + b * 16 + q * 4 + r], x);
            }
        }
        if (blockIdx.x == 0 && n == 0)
#pragma unroll
            for (int r = 0; r < 4; r++) cs0[r] += sv[0][r];
        if (blockIdx.x == 7 && n == 15)
#pragma unroll
            for (int r = 0; r < 4; r++) cs1[r] += sv[3][r];
        if ((grow == 0 || grow == HH - 1)) {
            int hi = (grow == 0) ? 0 : 1;
            if (blockIdx.x == 0 && n == 0)
#pragma unroll
                for (int r = 0; r < 4; r++)
                    wsf[OFF_COR + ((b * 2 + hi) * 2 + 0) * 16 + q * 4 + r] = sv[0][r];
            if (blockIdx.x == 7 && n == 15)
#pragma unroll
                for (int r = 0; r < 4; r++)
                    wsf[OFF_COR + ((b * 2 + hi) * 2 + 1) * 16 + q * 4 + r] = sv[3][r];
        }
    }
    if (blockIdx.x == 0 && n == 0)
#pragma unroll
        for (int r = 0; r < 4; r++) atomicAdd(&wsf[OFF_COL0 + b * 16 + q * 4 + r], cs0[r]);
    if (blockIdx.x == 7 && n == 15)
#pragma unroll
        for (int r = 0; r < 4; r++) atomicAdd(&wsf[OFF_COL1 + b * 16 + q * 4 + r], cs1[r]);
#pragma unroll
    for (int r = 0; r < 4; r++) {
        float x = tt[r];
#pragma unroll
        for (int d = 1; d < 16; d <<= 1) x += __shfl_xor(x, d, 64);
        tt[r] = x;
    }
    if (n == 0)
#pragma unroll
        for (int r = 0; r < 4; r++) part[wave][q * 4 + r] = tt[r];
    __syncthreads();
    if (tx < 16)
        atomicAdd(&wsf[OFF_TOT + b * 16 + tx],
                  part[0][tx] + part[1][tx] + part[2][tx] + part[3][tx]);
}

// ---------------- filter: assemble mean via edge algebra, build separable taps ----------------
__global__ void filter_kernel(const float* __restrict__ w3, const float* __restrict__ b3,
                              float* __restrict__ wsf) {
    int b = blockIdx.x, t = threadIdx.x;   // 160 threads
    __shared__ float red[160];
    float val = 0.f;
    if (t < 144) {
        int ic = t / 9, tap = t % 9, kh = tap / 3, kw = tap % 3;
        float T = wsf[OFF_TOT + b * 16 + ic];
        int hi = -1, wi = -1;
        if (kh == 0) { T -= wsf[OFF_ROW1 + b * 16 + ic]; hi = 1; }
        else if (kh == 2) { T -= wsf[OFF_ROW0 + b * 16 + ic]; hi = 0; }
        if (kw == 0) { T -= wsf[OFF_COL1 + b * 16 + ic]; wi = 1; }
        else if (kw == 2) { T -= wsf[OFF_COL0 + b * 16 + ic]; wi = 0; }
        if (hi >= 0 && wi >= 0) T += wsf[OFF_COR + ((b * 2 + hi) * 2 + wi) * 16 + ic];
        val = w3[t] * T;
    }
    red[t] = val;
    __syncthreads();
    __shared__ float sh_mean;
    if (t == 0) {
        float S = 0.f;
        for (int i = 0; i < 144; i++) S += red[i];
        sh_mean = b3[0] + S * (1.f / (float)PIX);
    }
    __syncthreads();
    float scale = fminf(2.5f, fmaxf(-2.5f, sh_mean));
    float sd = exp2f(scale);
    float fs = ceilf(3.f * sd + 0.5f);
    float e = 0.f, c = 0.f;
    if (t < 37) {
        float x = (float)(t - 18);
        if (fabsf(x) <= fs) {
            float qq = x / sd;
            e = __expf(-0.5f * qq * qq);
            c = -x / (sd * sd * sd * 6.28318530717958647692f) * e;
        }
    }
    __shared__ float sa[40], sb[40];
    if (t < 37) { sa[t] = e; sb[t] = fabsf(c); }
    __syncthreads();
    __shared__ float Se, Sc;
    if (t == 0) {
        float a = 0.f, d = 0.f;
        for (int i = 0; i < 37; i++) { a += sa[i]; d += sb[i]; }
        Se = a; Sc = d;
    }
    __syncthreads();
    if (t < 37) {
        wsf[OFF_EH + b * 37 + t] = e / Se;
        wsf[OFF_CH + b * 37 + t] = c / Sc;
    }
}

// ---------------- horizontal pass: batch -> xg (on the fly) -> t0..t3 ----------------
// Block = 2 rows x 512 cols, 4 px/thread sliding window. Skewed LDS (+1 word per 32)
// breaks the stride-4 8-way bank conflict. Small live set: 16 accumulators, no spill.
__device__ __forceinline__ int skw(int c) { return c + (c >> 5); }
__global__ __launch_bounds__(256, 4) void horiz_kernel(const float* __restrict__ batch,
                                                       const float* __restrict__ gcm,
                                                       const float* __restrict__ ehat,
                                                       const float* __restrict__ chat,
                                                       float* __restrict__ t) {
    __shared__ float xr[2][3][566];        // skewed: logical col 0..547 -> skw(c)
    int tx = threadIdx.x;
    int h0 = blockIdx.x * 2;
    int b  = blockIdx.y;
    const float* pb = batch + (size_t)(b * 3) * PIX;
    float g0 = gcm[0], g1 = gcm[1], g2 = gcm[2];
    float g3 = gcm[3], g4 = gcm[4], g5 = gcm[5];
    float g6 = gcm[6], g7 = gcm[7], g8 = gcm[8];
    for (int i = tx; i < 2 * 548; i += 256) {
        int r = i / 548, c = i - r * 548;
        int gw = c - 18;
        float v0 = 0.f, v1 = 0.f, v2 = 0.f;
        if (gw >= 0 && gw < WW) {
            size_t p = (size_t)(h0 + r) * WW + gw;
            v0 = pb[p]; v1 = pb[(size_t)PIX + p]; v2 = pb[2 * (size_t)PIX + p];
        }
        int cs = skw(c);
        xr[r][0][cs] = g0 * v0 + g1 * v1 + g2 * v2;
        xr[r][1][cs] = g3 * v0 + g4 * v1 + g5 * v2;
        xr[r][2][cs] = g6 * v0 + g7 * v1 + g8 * v2;
    }
    __syncthreads();
    int r = tx >> 7, colbase = (tx & 127) * 4;
    const float* eh = ehat + b * 37; const float* ch = chat + b * 37;
    float a0[4] = {}, a1[4] = {}, a2[4] = {}, a3[4] = {};
#pragma unroll 4
    for (int kk = 0; kk < 40; kk++) {
        int cs = skw(colbase + kk);
        float x0 = xr[r][0][cs], x1 = xr[r][1][cs], x2 = xr[r][2][cs];
#pragma unroll
        for (int i = 0; i < 4; i++) {
            int k = kk - i;
            if (k >= 0 && k < 37) {          // compile-time after unroll
                float ce = eh[k], cc = ch[k];
                a0[i] += ce * x0; a1[i] += ce * x1;
                a2[i] += ce * x2; a3[i] += cc * x0;
            }
        }
    }
    const size_t PL = (size_t)BN * PIX;
    size_t p = (size_t)b * PIX + (size_t)(h0 + r) * WW + colbase;
    *(float4*)&t[0 * PL + p] = make_float4(a0[0], a0[1], a0[2], a0[3]);
    *(float4*)&t[1 * PL + p] = make_float4(a1[0], a1[1], a1[2], a1[3]);
    *(float4*)&t[2 * PL + p] = make_float4(a2[0], a2[1], a2[2], a2[3]);
    *(float4*)&t[3 * PL + p] = make_float4(a3[0], a3[1], a3[2], a3[3]);
}

// ---------------- vertical pass + final math -> out ch0,1,5 (4-row sliding/thread) ----------------
__global__ __launch_bounds__(256, 4) void vert_kernel(const float* __restrict__ t,
                                                      const float* __restrict__ ehat,
                                                      const float* __restrict__ chat,
                                                      float* __restrict__ out) {
    int tx = threadIdx.x;
    int j = blockIdx.x * 64 + (tx & 63);
    int r0 = (blockIdx.y * 4 + (tx >> 6)) * 4;
    int b = blockIdx.z;
    const float* eh = ehat + b * 37; const float* ch = chat + b * 37;
    const size_t PL = (size_t)BN * PIX;
    const float* t0 = t + (size_t)b * PIX;
    float E[4] = {}, Ex[4] = {}, Ey[4] = {}, El[4] = {}, Ell[4] = {};
#pragma unroll 4
    for (int kk = 0; kk < 40; kk++) {
        int gr = r0 - 18 + kk;
        if (gr >= 0 && gr < HH) {
            size_t idx = (size_t)gr * WW + j;
            float v0 = t0[idx], v1 = t0[PL + idx], v2 = t0[2 * PL + idx], v3 = t0[3 * PL + idx];
#pragma unroll
            for (int i = 0; i < 4; i++) {
                int k = kk - i;
                if (k >= 0 && k < 37) {
                    float ce = eh[k], cc = ch[k];
                    E[i] += ce * v0; Ex[i] += cc * v0; Ey[i] += ce * v3;
                    El[i] += ce * v1; Ell[i] += ce * v2;
                }
            }
        }
    }
#pragma unroll
    for (int i = 0; i < 4; i++) {
        int h = r0 + i;
        float Hf = atanf(El[i] / (Ell[i] + EPSF));
        float S = logf((El[i] * El[i] + Ell[i] * Ell[i]) / (E[i] * E[i] + EPSF) + EPSF);
        float rx = Ex[i] / (E[i] + EPSF), ry = Ey[i] / (E[i] + EPSF);
        float Wv = atanf(rx * rx + ry * ry);
        size_t base = (size_t)(b * 6) * PIX + (size_t)h * WW + j;
        out[base] = Hf;
        out[base + PIX] = S;
        out[base + 5 * (size_t)PIX] = Wv;
    }
}

extern "C" void kernel_launch(void* const* d_in, const int* in_sizes, int n_in,
                              void* d_out, int out_size, void* d_ws, size_t ws_size,
                              hipStream_t stream) {
    const float* batch = (const float*)d_in[0];
    const float* gcm   = (const float*)d_in[1];
    const float* w1    = (const float*)d_in[2];
    const float* b1    = (const float*)d_in[3];
    const float* w2    = (const float*)d_in[4];
    const float* b2    = (const float*)d_in[5];
    const float* w3    = (const float*)d_in[6];
    const float* b3    = (const float*)d_in[7];
    float* out = (float*)d_out;

    if (ws_size < WS_NEEDED) return;

    float* wsf = (float*)d_ws;
    float* tpl = (float*)((char*)d_ws + OFF_TPB);
    float* ehat = wsf + OFF_EH;
    float* chat = wsf + OFF_CH;

    prep_kernel<<<dim3(1), dim3(256), 0, stream>>>(w1, w2, wsf);
    conv12_kernel<<<dim3(8, 64, 8), dim3(256), 0, stream>>>(
        batch, (const unsigned short*)(wsf + OFF_W1R), b1,
        (const unsigned short*)(wsf + OFF_WR), b2, wsf, out);
    filter_kernel<<<dim3(8), dim3(160), 0, stream>>>(w3, b3, wsf);
    horiz_kernel<<<dim3(256, 8), dim3(256), 0, stream>>>(batch, gcm, ehat, chat, tpl);
    vert_kernel<<<dim3(8, 32, 8), dim3(256), 0, stream>>>(tpl, ehat, chat, out);
}